// Round 1
// baseline (349.415 us; speedup 1.0000x reference)
//
#include <hip/hip_runtime.h>
#include <hip/hip_bf16.h>

#define SQ 2048
#define NB 2
#define NH 16
#define HN 128
#define SBH 4096              // element stride for s index: B*NH*HN
#define QBLK 64
#define NWAVE 4
#define SCALE 0.08838834764831845f   // 1/sqrt(128)

#define KP 136   // K_lds pitch (bf16 elems): bank-conflict-free, 16B aligned rows
#define VP 40    // Vt_lds pitch: 2-way conflict (free), 16B aligned rows
#define PP 40    // P_lds pitch

typedef __attribute__((ext_vector_type(4))) float f32x4;
typedef __attribute__((ext_vector_type(8))) short bf16x8;

__device__ __forceinline__ short f2bf(float f) {
    union { float f; unsigned u; } v; v.f = f;
    unsigned r = v.u + 0x7fffu + ((v.u >> 16) & 1u);
    return (short)(r >> 16);
}

__global__ __launch_bounds__(256)
void attn_fwd(const float* __restrict__ Q, const float* __restrict__ K,
              const float* __restrict__ V, float* __restrict__ O) {
    __shared__ __align__(16) short K_lds[32 * KP];
    __shared__ __align__(16) short Vt_lds[HN * VP];
    __shared__ __align__(16) short P_lds[NWAVE][16 * PP];

    const int qt = (int)(gridDim.x - 1 - blockIdx.x);   // heavy tiles dispatch first
    const int bh = (int)blockIdx.y;
    const size_t bh_off = (size_t)(bh >> 4) * 2048 + (size_t)(bh & 15) * 128;

    const int t    = threadIdx.x;
    const int lane = t & 63;
    const int wv   = t >> 6;
    const int l15  = lane & 15;
    const int lhi  = lane >> 4;    // 0..3

    // ---- Q fragments (A operand), held in registers for the whole kernel ----
    bf16x8 q_frag[4];
    {
        const int qrow = qt * QBLK + wv * 16 + l15;
        const float* qp = Q + (size_t)qrow * SBH + bh_off + lhi * 8;
        #pragma unroll
        for (int kk = 0; kk < 4; ++kk) {
            f32x4 a = *(const f32x4*)(qp + kk * 32);
            f32x4 b = *(const f32x4*)(qp + kk * 32 + 4);
            #pragma unroll
            for (int i = 0; i < 4; ++i) {
                q_frag[kk][i]     = f2bf(a[i]);
                q_frag[kk][4 + i] = f2bf(b[i]);
            }
        }
    }

    float m_r[4], l_r[4];
    #pragma unroll
    for (int r = 0; r < 4; ++r) { m_r[r] = -1e30f; l_r[r] = 0.f; }
    f32x4 o_acc[8];
    #pragma unroll
    for (int nn = 0; nn < 8; ++nn) o_acc[nn] = (f32x4){0.f, 0.f, 0.f, 0.f};

    const int row0    = qt * QBLK + wv * 16 + lhi * 4;  // first of this lane's 4 rows
    const int wrowmax = qt * QBLK + wv * 16 + 15;       // last q row of this wave
    const int stg_row = t >> 3;                          // 0..31
    const int stg_d   = (t & 7) * 16;                    // 0,16,...,112

    const int nt = qt * 2 + 2;                           // KV tiles of 32 up to diagonal
    for (int it = 0; it < nt; ++it) {
        const int kv0 = it * 32;
        __syncthreads();
        // ---- stage K tile [32][128] -> bf16 LDS ----
        {
            const float* kp = K + (size_t)(kv0 + stg_row) * SBH + bh_off + stg_d;
            f32x4 a = *(const f32x4*)(kp + 0);
            f32x4 b = *(const f32x4*)(kp + 4);
            f32x4 c = *(const f32x4*)(kp + 8);
            f32x4 d = *(const f32x4*)(kp + 12);
            bf16x8 h0, h1;
            #pragma unroll
            for (int i = 0; i < 4; ++i) {
                h0[i] = f2bf(a[i]); h0[4 + i] = f2bf(b[i]);
                h1[i] = f2bf(c[i]); h1[4 + i] = f2bf(d[i]);
            }
            *(bf16x8*)&K_lds[stg_row * KP + stg_d]     = h0;
            *(bf16x8*)&K_lds[stg_row * KP + stg_d + 8] = h1;
            // ---- stage V tile transposed: Vt[d][j] ----
            const float* vp = V + (size_t)(kv0 + stg_row) * SBH + bh_off + stg_d;
            f32x4 e = *(const f32x4*)(vp + 0);
            f32x4 f = *(const f32x4*)(vp + 4);
            f32x4 g = *(const f32x4*)(vp + 8);
            f32x4 h = *(const f32x4*)(vp + 12);
            #pragma unroll
            for (int i = 0; i < 4; ++i) {
                Vt_lds[(stg_d + i)      * VP + stg_row] = f2bf(e[i]);
                Vt_lds[(stg_d + 4 + i)  * VP + stg_row] = f2bf(f[i]);
                Vt_lds[(stg_d + 8 + i)  * VP + stg_row] = f2bf(g[i]);
                Vt_lds[(stg_d + 12 + i) * VP + stg_row] = f2bf(h[i]);
            }
        }
        __syncthreads();

        if (kv0 > wrowmax) continue;   // whole tile masked for this wave (uniform)

        // ---- S = Q K^T (16x32 per wave) ----
        f32x4 s_acc[2];
        s_acc[0] = (f32x4){0.f, 0.f, 0.f, 0.f};
        s_acc[1] = (f32x4){0.f, 0.f, 0.f, 0.f};
        #pragma unroll
        for (int jj = 0; jj < 2; ++jj) {
            #pragma unroll
            for (int kk = 0; kk < 4; ++kk) {
                bf16x8 bfr = *(const bf16x8*)&K_lds[(jj * 16 + l15) * KP + kk * 32 + lhi * 8];
                s_acc[jj] = __builtin_amdgcn_mfma_f32_16x16x32_bf16(q_frag[kk], bfr, s_acc[jj], 0, 0, 0);
            }
        }

        // ---- online softmax (wave-parallel over 16-lane groups) ----
        const int col0 = kv0 + l15;
        #pragma unroll
        for (int r = 0; r < 4; ++r) {
            float s0 = s_acc[0][r] * SCALE;
            float s1 = s_acc[1][r] * SCALE;
            const int rg = row0 + r;
            if (col0 > rg)      s0 = -1e30f;
            if (col0 + 16 > rg) s1 = -1e30f;
            float mx = fmaxf(s0, s1);
            #pragma unroll
            for (int m = 1; m < 16; m <<= 1) mx = fmaxf(mx, __shfl_xor(mx, m));
            const float mnew = fmaxf(m_r[r], mx);
            const float p0 = __expf(s0 - mnew);
            const float p1 = __expf(s1 - mnew);
            const float corr = __expf(m_r[r] - mnew);
            m_r[r] = mnew;
            float ps = p0 + p1;
            #pragma unroll
            for (int m = 1; m < 16; m <<= 1) ps += __shfl_xor(ps, m);
            l_r[r] = l_r[r] * corr + ps;
            #pragma unroll
            for (int nn = 0; nn < 8; ++nn) o_acc[nn][r] *= corr;
            const int rl = lhi * 4 + r;
            P_lds[wv][rl * PP + l15]      = f2bf(p0);
            P_lds[wv][rl * PP + 16 + l15] = f2bf(p1);
        }

        // ---- O += P V  (P: A operand from LDS; Vt: B operand contiguous) ----
        bf16x8 pa = *(const bf16x8*)&P_lds[wv][l15 * PP + lhi * 8];
        #pragma unroll
        for (int nn = 0; nn < 8; ++nn) {
            bf16x8 bv = *(const bf16x8*)&Vt_lds[(nn * 16 + l15) * VP + lhi * 8];
            o_acc[nn] = __builtin_amdgcn_mfma_f32_16x16x32_bf16(pa, bv, o_acc[nn], 0, 0, 0);
        }
    }

    // ---- epilogue: O / l ----
    #pragma unroll
    for (int r = 0; r < 4; ++r) {
        const float inv = 1.0f / l_r[r];
        float* op = O + (size_t)(row0 + r) * SBH + bh_off + l15;
        #pragma unroll
        for (int nn = 0; nn < 8; ++nn) op[nn * 16] = o_acc[nn][r] * inv;
    }
}

extern "C" void kernel_launch(void* const* d_in, const int* in_sizes, int n_in,
                              void* d_out, int out_size, void* d_ws, size_t ws_size,
                              hipStream_t stream) {
    const float* q = (const float*)d_in[0];
    const float* k = (const float*)d_in[1];
    const float* v = (const float*)d_in[2];
    // d_in[3] is the causal mask; it is triu(ones,k=1) by construction — applied analytically.
    float* out = (float*)d_out;
    dim3 grid(SQ / QBLK, NB * NH);
    attn_fwd<<<grid, 256, 0, stream>>>(q, k, v, out);
}